// Round 6
// baseline (328.820 us; speedup 1.0000x reference)
//
#include <hip/hip_runtime.h>
#include <hip/hip_bf16.h>

#define OMEGA0 30.0f
#define IN_DIM 512
#define OUT_DIM 512
#define THREADS 256

typedef _Float16 f16;
typedef __attribute__((ext_vector_type(8))) _Float16 f16x8;
typedef __attribute__((ext_vector_type(4))) float f32x4;

// ---------------- pre-kernel 1: thetaW window layout ----------------
// Window wid = (nt*16 + kk)*4 + fn  (nt:8 tiles of 64 cols, kk:16, fn:4), 1KB each.
// Lane l, elem e: thetaW[wid*512 + l*8 + e] = f16(30*theta[(nt*64+fn*16+(l&15))*512 + kk*32 + (l>>4)*8 + e])
// i.e. lane l's 16B IS its MFMA B-fragment for (kk, fn) — main-kernel reads are
// 64-lane contiguous 1KB bursts straight from L2.
__global__ void make_thetaW_kernel(const float* __restrict__ theta, f16* __restrict__ thetaW) {
    int t = threadIdx.x, w = t >> 6, lane = t & 63;
    int wid = blockIdx.x * 4 + w;            // 0..511
    int fn = wid & 3, kk = (wid >> 2) & 15, nt = wid >> 6;
    int col = nt * 64 + fn * 16 + (lane & 15);
    int k = kk * 32 + (lane >> 4) * 8;
    const float* src = theta + (long)col * IN_DIM + k;
    f32x4 a = *(const f32x4*)src;
    f32x4 b = *(const f32x4*)(src + 4);
    f16x8 o;
#pragma unroll
    for (int i = 0; i < 4; i++) { o[i] = (f16)(OMEGA0 * a[i]); o[4 + i] = (f16)(OMEGA0 * b[i]); }
    *(f16x8*)&thetaW[(long)wid * 512 + lane * 8] = o;
}

// ---------------- pre-kernel 2: bias[o] = 30*sum_k theta[o][k] + phi[o] ----------------
__global__ void make_bias_kernel(const float* __restrict__ theta, const float* __restrict__ phi,
                                 float* __restrict__ bias) {
    int w = threadIdx.x >> 6, lane = threadIdx.x & 63;
    int o = blockIdx.x * 4 + w;
    const float* row = theta + (long)o * IN_DIM + lane * 8;
    f32x4 a = *(const f32x4*)row;
    f32x4 b = *(const f32x4*)(row + 4);
    float s = a[0] + a[1] + a[2] + a[3] + b[0] + b[1] + b[2] + b[3];
#pragma unroll
    for (int off = 32; off; off >>= 1) s += __shfl_down(s, off, 64);
    if (lane == 0) bias[o] = OMEGA0 * s + phi[o];
}

// ---------------- main GEMM + cos epilogue: NO LDS, NO BARRIER ----------------
// 4-wave blocks, wave-tile 32x64 (block 128x64). B-fragments read directly from
// the L2-resident window layout (depth-2 reg ring). A streamed global->reg with
// fp32->f16 cvt, depth-3 ring. Iteration order: cvt A(kk) FIRST (slot is about
// to be reused — (kk+3)%3 == kk%3), then issue B(kk+2), A(kk+3), then MFMA(kk).
// 4 independent blocks/CU at staggered phases overlap loads/MFMA/epilogue.
__launch_bounds__(THREADS, 4)
__global__ void siren_gemm_kernel(const float* __restrict__ x, const f16* __restrict__ thetaW,
                                  const float* __restrict__ bias, float* __restrict__ out) {
    // XCD-chunked swizzle: 8 consecutive swz (same mt, nt=0..7) run adjacent on
    // one XCD -> 256KB A-panel gets 8x reuse in that XCD's L2.
    int nwg = gridDim.x;
    int bid = blockIdx.x;
    int cpx = nwg >> 3;
    int swz = (bid & 7) * cpx + (bid >> 3);
    int mt = swz >> 3;           // 1024 m-tiles of 128 rows
    int nt = swz & 7;            // 8 n-tiles of 64 cols
    long m0 = (long)mt * 128;
    int n0 = nt * 64;

    int t = threadIdx.x, w = t >> 6, lane = t & 63;
    int lr = lane & 15, lk = lane >> 4;

    const float* aBase = x + (m0 + w * 32 + lr) * (long)IN_DIM + lk * 8;
    const f16* wBase = thetaW + (long)nt * (16 * 4 * 512) + lane * 8;  // + (kk*4+fn)*512

    f32x4 acc[2][4] = {};        // 32 VGPR
    f32x4 ar[3][2][2];           // 48 VGPR, depth-3 A ring (static-indexed via full unroll)
    f16x8 bf[3][4];              // 24 VGPR, depth-2 B ring in 3 slots

    // ---- prologue: B kk=0,1 ; A kk=0,1,2 ----
#pragma unroll
    for (int s = 0; s < 2; s++)
#pragma unroll
        for (int fn = 0; fn < 4; fn++)
            bf[s][fn] = *(const f16x8*)&wBase[(s * 4 + fn) * 512];
#pragma unroll
    for (int s = 0; s < 3; s++)
#pragma unroll
        for (int fm = 0; fm < 2; fm++) {
            const float* p = aBase + (long)fm * 16 * IN_DIM + s * 32;
            ar[s][fm][0] = *(const f32x4*)p;
            ar[s][fm][1] = *(const f32x4*)(p + 4);
        }

    // ---- barrier-free K-loop, fully unrolled ----
#pragma unroll
    for (int kk = 0; kk < 16; kk++) {
        int asl = kk % 3;        // A slot holding kk (compile-time after unroll)
        int bsl = kk % 3;        // B slot holding kk

        // 1) cvt A(kk) out of its slot BEFORE the slot is re-issued below.
        f16x8 af[2];
#pragma unroll
        for (int fm = 0; fm < 2; fm++)
#pragma unroll
            for (int i = 0; i < 4; i++) {
                af[fm][i]     = (f16)ar[asl][fm][0][i];
                af[fm][4 + i] = (f16)ar[asl][fm][1][i];
            }

        // 2) issue B(kk+2) then A(kk+3) (B first: in-order vmcnt never forces
        //    the not-yet-needed A ahead of schedule).
        if (kk + 2 < 16) {
#pragma unroll
            for (int fn = 0; fn < 4; fn++)
                bf[(kk + 2) % 3][fn] = *(const f16x8*)&wBase[((kk + 2) * 4 + fn) * 512];
        }
        if (kk + 3 < 16) {
#pragma unroll
            for (int fm = 0; fm < 2; fm++) {
                const float* p = aBase + (long)fm * 16 * IN_DIM + (kk + 3) * 32;
                ar[asl][fm][0] = *(const f32x4*)p;
                ar[asl][fm][1] = *(const f32x4*)(p + 4);
            }
        }

        // 3) MFMA(kk)
#pragma unroll
        for (int fn = 0; fn < 4; fn++) {
            acc[0][fn] = __builtin_amdgcn_mfma_f32_16x16x32_f16(af[0], bf[bsl][fn], acc[0][fn], 0, 0, 0);
            acc[1][fn] = __builtin_amdgcn_mfma_f32_16x16x32_f16(af[1], bf[bsl][fn], acc[1][fn], 0, 0, 0);
        }
    }

    // ---- epilogue: cos(acc + bias[col]), non-temporal stores ----
#pragma unroll
    for (int fn = 0; fn < 4; fn++) {
        int col = n0 + fn * 16 + lr;
        float bv = bias[col];
#pragma unroll
        for (int fm = 0; fm < 2; fm++) {
            long row0 = m0 + w * 32 + fm * 16 + lk * 4;
#pragma unroll
            for (int r = 0; r < 4; r++) {
                float v = __cosf(acc[fm][fn][r] + bv);
                __builtin_nontemporal_store(v, &out[(row0 + r) * OUT_DIM + col]);
            }
        }
    }
}

extern "C" void kernel_launch(void* const* d_in, const int* in_sizes, int n_in,
                              void* d_out, int out_size, void* d_ws, size_t ws_size,
                              hipStream_t stream) {
    const float* x     = (const float*)d_in[0];
    const float* theta = (const float*)d_in[1];
    const float* phi   = (const float*)d_in[2];
    float* out = (float*)d_out;

    size_t thetaW_bytes = (size_t)512 * 512 * sizeof(f16);      // 512 KB (512 windows x 1KB)
    size_t need = thetaW_bytes + OUT_DIM * sizeof(float);       // + 2 KB bias
    if (ws_size < need) return;

    f16*   thetaW = (f16*)d_ws;
    float* bias   = (float*)((char*)d_ws + thetaW_bytes);

    int Brows = in_sizes[0] / IN_DIM;  // 131072

    make_thetaW_kernel<<<128, 256, 0, stream>>>(theta, thetaW);
    make_bias_kernel<<<OUT_DIM / 4, 256, 0, stream>>>(theta, phi, bias);

    int grid = (Brows / 128) * (OUT_DIM / 64);  // 1024 * 8 = 8192
    siren_gemm_kernel<<<grid, THREADS, 0, stream>>>(x, thetaW, bias, out);
}

// Round 8
// 294.977 us; speedup vs baseline: 1.1147x; 1.1147x over previous
//
#include <hip/hip_runtime.h>
#include <hip/hip_bf16.h>

#define OMEGA0 30.0f
#define IN_DIM 512
#define OUT_DIM 512
#define BM 256
#define BN 64
#define THREADS 512

typedef _Float16 f16;
typedef __attribute__((ext_vector_type(2))) __fp16 fp16x2;   // cvt_pkrtz return type
typedef __attribute__((ext_vector_type(8))) _Float16 f16x8;
typedef __attribute__((ext_vector_type(4))) float f32x4;

// ---------------- pre-kernel 1: theta16[o][k] = f16(30*theta[o][k]) (row-major) ----------------
__global__ void cvt_theta_kernel(const float* __restrict__ theta, f16* __restrict__ theta16) {
    int idx = (blockIdx.x * 256 + threadIdx.x) * 8;
    f32x4 a = *(const f32x4*)(theta + idx);
    f32x4 b = *(const f32x4*)(theta + idx + 4);
    f16x8 o;
#pragma unroll
    for (int i = 0; i < 4; i++) { o[i] = (f16)(OMEGA0 * a[i]); o[4 + i] = (f16)(OMEGA0 * b[i]); }
    *(f16x8*)(theta16 + idx) = o;
}

// ---------------- pre-kernel 2: bias[o] = 30*sum_k theta[o][k] + phi[o] ----------------
__global__ void make_bias_kernel(const float* __restrict__ theta, const float* __restrict__ phi,
                                 float* __restrict__ bias) {
    int w = threadIdx.x >> 6, lane = threadIdx.x & 63;
    int o = blockIdx.x * 4 + w;
    const float* row = theta + (long)o * IN_DIM + lane * 8;
    f32x4 a = *(const f32x4*)row;
    f32x4 b = *(const f32x4*)(row + 4);
    float s = a[0] + a[1] + a[2] + a[3] + b[0] + b[1] + b[2] + b[3];
#pragma unroll
    for (int off = 32; off; off >>= 1) s += __shfl_down(s, off, 64);
    if (lane == 0) bias[o] = OMEGA0 * s + phi[o];
}

// ---------------- main GEMM + cos epilogue ----------------
// BN=64 n-tile, full K=512 of B resident in LDS as 64 x 1KB MFMA-fragment
// windows (64 KB -> 2 blocks/CU). 512 thr / 8 waves, wave-tile 32x64, each wave
// streams its 32 exclusive A rows global->reg (pkrtz cvt) with a depth-3 ring;
// B frags ds_read from windows (64-lane contiguous -> zero conflicts), depth-2.
// Barrier-free K-loop after the single stage barrier. launch_bounds(512,2)
// keeps the compiler in relaxed-VGPR mode so the rings SURVIVE (rounds 2/4/6:
// declaring ",4" crushed VGPR to 44-64 and serialized all loads). Target
// actual VGPR <= 128 so HW gives 4 waves/EU anyway.
__launch_bounds__(THREADS, 2)
__global__ void siren_gemm_kernel(const float* __restrict__ x, const f16* __restrict__ theta16,
                                  const float* __restrict__ bias, float* __restrict__ out) {
    __shared__ f16 ldsB[BN * IN_DIM];   // 64 KB, window layout [(kk*4+fn)*512 + lane*8]

    // XCD-chunked swizzle: the 8 n-tiles of an m-strip run adjacent on one XCD.
    int nwg = gridDim.x;
    int bid = blockIdx.x;
    int cpx = nwg >> 3;
    int swz = (bid & 7) * cpx + (bid >> 3);
    int mt = swz >> 3;           // 512 m-strips of 256 rows
    int nt = swz & 7;            // 8 n-tiles of 64 cols
    long m0 = (long)mt * BM;
    int n0 = nt * BN;

    int t = threadIdx.x, w = t >> 6, lane = t & 63;
    int lr = lane & 15, lk = lane >> 4;

    // ---- one-time B stage: wave w stages windows w*8 .. w*8+7 ----
    // Window (kk,fn) chunk l holds theta30[col=n0+fn*16+(l&15)][k=kk*32+(l>>4)*8..+8]
    // == lane l's B-fragment. LDS dest wave-uniform + lane*16 (hw), src per-lane.
#pragma unroll
    for (int j = 0; j < 8; j++) {
        int wid = w * 8 + j;
        int kk = wid >> 2, fn = wid & 3;
        const f16* p = theta16 + (long)(n0 + fn * 16 + lr) * IN_DIM + kk * 32 + lk * 8;
        __builtin_amdgcn_global_load_lds(
            (const __attribute__((address_space(1))) char*)(const char*)p,
            (__attribute__((address_space(3))) char*)(char*)(&ldsB[wid * 512]),
            16, 0, 0);
    }
    __syncthreads();   // the only barrier

    // ---- barrier-free K-loop ----
    f32x4 acc[2][4] = {};        // 32 VGPR
    f32x4 ar[3][2][2];           // 48 VGPR depth-3 A ring (static idx via full unroll)
    f16x8 bf[2][4];              // 16 VGPR depth-2 B ring
    const float* aBase = x + (m0 + w * 32 + lr) * (long)IN_DIM + lk * 8;

    // prologue: A kk=0,1,2 ; B kk=0
#pragma unroll
    for (int s = 0; s < 3; s++)
#pragma unroll
        for (int fm = 0; fm < 2; fm++) {
            const float* p = aBase + (long)fm * 16 * IN_DIM + s * 32;
            ar[s][fm][0] = *(const f32x4*)p;
            ar[s][fm][1] = *(const f32x4*)(p + 4);
        }
#pragma unroll
    for (int fn = 0; fn < 4; fn++)
        bf[0][fn] = *(const f16x8*)&ldsB[fn * 512 + lane * 8];

#pragma unroll
    for (int kk = 0; kk < 16; kk++) {
        int asl = kk % 3;        // compile-time after unroll

        // 1) cvt A(kk) out of its slot (packed RTZ: 8 ops for 16 elems)
        f16x8 af[2];
#pragma unroll
        for (int fm = 0; fm < 2; fm++) {
            union { fp16x2 h[4]; f16x8 v; } u;
#pragma unroll
            for (int i = 0; i < 2; i++) {
                u.h[i]     = __builtin_amdgcn_cvt_pkrtz(ar[asl][fm][0][2 * i], ar[asl][fm][0][2 * i + 1]);
                u.h[2 + i] = __builtin_amdgcn_cvt_pkrtz(ar[asl][fm][1][2 * i], ar[asl][fm][1][2 * i + 1]);
            }
            af[fm] = u.v;
        }

        // 2) reissue freed slot with A(kk+3)
        if (kk + 3 < 16) {
#pragma unroll
            for (int fm = 0; fm < 2; fm++) {
                const float* p = aBase + (long)fm * 16 * IN_DIM + (kk + 3) * 32;
                ar[asl][fm][0] = *(const f32x4*)p;
                ar[asl][fm][1] = *(const f32x4*)(p + 4);
            }
        }

        // 3) ds_read B(kk+1) (contiguous 1KB bursts, conflict-free)
        if (kk + 1 < 16) {
#pragma unroll
            for (int fn = 0; fn < 4; fn++)
                bf[(kk + 1) & 1][fn] = *(const f16x8*)&ldsB[((kk + 1) * 4 + fn) * 512 + lane * 8];
        }

        // 4) MFMA(kk)
#pragma unroll
        for (int fn = 0; fn < 4; fn++) {
            acc[0][fn] = __builtin_amdgcn_mfma_f32_16x16x32_f16(af[0], bf[kk & 1][fn], acc[0][fn], 0, 0, 0);
            acc[1][fn] = __builtin_amdgcn_mfma_f32_16x16x32_f16(af[1], bf[kk & 1][fn], acc[1][fn], 0, 0, 0);
        }
    }

    // ---- epilogue: cos(acc + bias[col]), non-temporal stores ----
#pragma unroll
    for (int fn = 0; fn < 4; fn++) {
        int col = n0 + fn * 16 + lr;
        float bv = bias[col];
#pragma unroll
        for (int fm = 0; fm < 2; fm++) {
            long row0 = m0 + w * 32 + fm * 16 + lk * 4;
#pragma unroll
            for (int r = 0; r < 4; r++) {
                float v = __cosf(acc[fm][fn][r] + bv);
                __builtin_nontemporal_store(v, &out[(row0 + r) * OUT_DIM + col]);
            }
        }
    }
}

extern "C" void kernel_launch(void* const* d_in, const int* in_sizes, int n_in,
                              void* d_out, int out_size, void* d_ws, size_t ws_size,
                              hipStream_t stream) {
    const float* x     = (const float*)d_in[0];
    const float* theta = (const float*)d_in[1];
    const float* phi   = (const float*)d_in[2];
    float* out = (float*)d_out;

    size_t theta16_bytes = (size_t)OUT_DIM * IN_DIM * sizeof(f16);  // 512 KB
    size_t need = theta16_bytes + OUT_DIM * sizeof(float);          // + 2 KB bias
    if (ws_size < need) return;

    f16*   theta16 = (f16*)d_ws;
    float* bias    = (float*)((char*)d_ws + theta16_bytes);

    int Brows = in_sizes[0] / IN_DIM;  // 131072

    cvt_theta_kernel<<<(OUT_DIM * IN_DIM / 8 + 255) / 256, 256, 0, stream>>>(theta, theta16);
    make_bias_kernel<<<OUT_DIM / 4, 256, 0, stream>>>(theta, phi, bias);

    int grid = (Brows / BM) * (OUT_DIM / BN);  // 512 * 8 = 4096
    siren_gemm_kernel<<<grid, THREADS, 0, stream>>>(x, theta16, bias, out);
}